// Round 2
// baseline (492.155 us; speedup 1.0000x reference)
//
#include <hip/hip_runtime.h>
#include <hip/hip_bf16.h>
#include <cstdint>

typedef __bf16 bf16x8 __attribute__((ext_vector_type(8)));
typedef float f32x4 __attribute__((ext_vector_type(4)));
typedef unsigned short u16x8 __attribute__((ext_vector_type(8)));

__device__ __forceinline__ unsigned short f2bf(float f) {
  union { float f; unsigned int u; } v; v.f = f;
  unsigned int r = v.u + 0x7fffu + ((v.u >> 16) & 1u);
  return (unsigned short)(r >> 16);
}

// async global->LDS, 16B per lane. LDS layout must be lane-contiguous.
__device__ __forceinline__ void gload_lds16(const void* g, void* l) {
  __builtin_amdgcn_global_load_lds(
      (const __attribute__((address_space(1))) unsigned int*)g,
      (__attribute__((address_space(3))) unsigned int*)l, 16, 0, 0);
}

// ---------------- convert x: fp32 -> bf16 ----------------
__global__ void cvt_x_kernel(const float* __restrict__ x,
                             unsigned short* __restrict__ xb, int n4) {
  int i = blockIdx.x * blockDim.x + threadIdx.x;
  if (i >= n4) return;
  float4 v = ((const float4*)x)[i];
  ushort4 o;
  o.x = f2bf(v.x); o.y = f2bf(v.y); o.z = f2bf(v.z); o.w = f2bf(v.w);
  ((ushort4*)xb)[i] = o;
}

// ------- transpose+convert weights: w[K][N] fp32 -> wt[N][K] bf16 -------
__global__ void cvt_wt_kernel(const float* __restrict__ w,
                              unsigned short* __restrict__ wt, int K, int N) {
  __shared__ float tile[32][33];
  int nb = blockIdx.x * 32, kb = blockIdx.y * 32;
  int tx = threadIdx.x & 31, ty = threadIdx.x >> 5;
#pragma unroll
  for (int i = 0; i < 32; i += 8)
    tile[ty + i][tx] = w[(size_t)(kb + ty + i) * N + nb + tx];
  __syncthreads();
#pragma unroll
  for (int i = 0; i < 32; i += 8)
    wt[(size_t)(nb + ty + i) * K + kb + tx] = f2bf(tile[tx][ty + i]);
}

// ---------------- 128x128 bf16 GEMM, C = A[M,K] @ Bt[N,K]^T ----------------
template <int EPI>
__global__ __launch_bounds__(256, 2)
void gemm128_kernel(const unsigned short* __restrict__ A,
                    const unsigned short* __restrict__ Bt,
                    void* __restrict__ C, int M, int N, int K) {
  __shared__ unsigned short As[128 * 72];
  __shared__ unsigned short Bs[128 * 72];
  const int tid = threadIdx.x;
  const int lane = tid & 63, wid = tid >> 6;
  const int m16 = lane & 15, quad = lane >> 4;
  const int rowBase = blockIdx.y * 128, colBase = blockIdx.x * 128;
  const int wm = (wid >> 1) * 64, wn = (wid & 1) * 64;

  f32x4 acc[4][4] = {};

  for (int k0 = 0; k0 < K; k0 += 64) {
    bf16x8 ra[4], rb[4];
#pragma unroll
    for (int it = 0; it < 4; it++) {
      int i = tid + it * 256;
      int r = i >> 3, kc = (i & 7) * 8;
      ra[it] = *(const bf16x8*)(A + (size_t)(rowBase + r) * K + k0 + kc);
      rb[it] = *(const bf16x8*)(Bt + (size_t)(colBase + r) * K + k0 + kc);
    }
#pragma unroll
    for (int it = 0; it < 4; it++) {
      int i = tid + it * 256;
      int r = i >> 3, kc = (i & 7) * 8;
      *(bf16x8*)(As + r * 72 + kc) = ra[it];
      *(bf16x8*)(Bs + r * 72 + kc) = rb[it];
    }
    __syncthreads();

    bf16x8 af[4][2], bfr[4][2];
#pragma unroll
    for (int rt = 0; rt < 4; rt++) {
      const unsigned short* p = As + (wm + rt * 16 + m16) * 72 + quad * 8;
      af[rt][0] = *(const bf16x8*)(p);
      af[rt][1] = *(const bf16x8*)(p + 32);
    }
#pragma unroll
    for (int ct = 0; ct < 4; ct++) {
      const unsigned short* p = Bs + (wn + ct * 16 + m16) * 72 + quad * 8;
      bfr[ct][0] = *(const bf16x8*)(p);
      bfr[ct][1] = *(const bf16x8*)(p + 32);
    }
#pragma unroll
    for (int rt = 0; rt < 4; rt++)
#pragma unroll
      for (int ct = 0; ct < 4; ct++) {
        acc[rt][ct] = __builtin_amdgcn_mfma_f32_16x16x32_bf16(
            af[rt][0], bfr[ct][0], acc[rt][ct], 0, 0, 0);
        acc[rt][ct] = __builtin_amdgcn_mfma_f32_16x16x32_bf16(
            af[rt][1], bfr[ct][1], acc[rt][ct], 0, 0, 0);
      }
    __syncthreads();
  }

#pragma unroll
  for (int rt = 0; rt < 4; rt++)
#pragma unroll
    for (int ct = 0; ct < 4; ct++)
#pragma unroll
      for (int r = 0; r < 4; r++) {
        int grow = rowBase + wm + rt * 16 + quad * 4 + r;
        int gcol = colBase + wn + ct * 16 + m16;
        float v = acc[rt][ct][r];
        if (EPI == 0)
          ((unsigned short*)C)[(size_t)grow * N + gcol] = f2bf(v);
        else
          ((float*)C)[(size_t)grow * N + gcol] = v;
      }
}

// ------- transpose V out of qkv: VT[(b*16+h)*64+d][t] (bf16) -------
__global__ void vtrans_kernel(const unsigned short* __restrict__ qkv,
                              unsigned short* __restrict__ VT) {
  __shared__ unsigned short tile[64 * 72];
  const int tid = threadIdx.x;
  const int bh = blockIdx.y, bb = bh >> 4, hh = bh & 15;
  const int t0 = blockIdx.x * 64;
  const size_t bo = (size_t)bb * 2048 * 3072;
#pragma unroll
  for (int it = 0; it < 2; it++) {
    int i = tid + it * 256;
    int t = i >> 3, dc = (i & 7) * 8;
    *(bf16x8*)(tile + t * 72 + dc) =
        *(const bf16x8*)(qkv + bo + (size_t)(t0 + t) * 3072 + 2048 + hh * 64 + dc);
  }
  __syncthreads();
#pragma unroll
  for (int it = 0; it < 2; it++) {
    int i = tid + it * 256;
    int d = i >> 3, tc = (i & 7) * 8;
    u16x8 v;
#pragma unroll
    for (int j = 0; j < 8; j++) v[j] = tile[(tc + j) * 72 + d];
    *(u16x8*)(VT + ((size_t)bh * 64 + d) * 2048 + t0 + tc) = v;
  }
}

// ---------------- flash attention (128 q-rows/block, 128-key stages) -------
// qkv: bf16 [4][2048][3072]; VT: bf16 [64][64][2048]; yb: bf16 [4][2048][1024]
__global__ __launch_bounds__(256, 2)
void attn_kernel(const unsigned short* __restrict__ qkv,
                 const unsigned short* __restrict__ VT,
                 unsigned short* __restrict__ yb) {
  __shared__ unsigned short Ks[128 * 64];      // [key][d], lane-contiguous
  __shared__ unsigned short Vt[64 * 128];      // [d][key], lane-contiguous
  __shared__ unsigned short Ps[4 * 16 * 136];  // per-wave P [16 qrows][128 keys]

  const int tid = threadIdx.x;
  const int lane = tid & 63, wave = tid >> 6;
  const int m16 = lane & 15, quad = lane >> 4;
  const int bh = blockIdx.y, bb = bh >> 4, hh = bh & 15;
  const int QT = (gridDim.x - 1) - blockIdx.x;  // big blocks first
  const int q0 = QT * 128;
  const int qw = q0 + wave * 32;  // this wave's 32 q-rows

  const size_t bo = (size_t)bb * 2048 * 3072;
  const float SCL = 0.125f * 1.44269504088896f;  // exp2 domain

  // Q fragments (A-layout), resident all kernel
  bf16x8 aQ[2][2];
#pragma unroll
  for (int qf = 0; qf < 2; qf++) {
    const unsigned short* qb =
        qkv + bo + (size_t)(qw + qf * 16 + m16) * 3072 + hh * 64;
    aQ[qf][0] = *(const bf16x8*)(qb + quad * 8);
    aQ[qf][1] = *(const bf16x8*)(qb + 32 + quad * 8);
  }

  float mi[2][4], li[2][4];
  f32x4 o[2][4] = {};
#pragma unroll
  for (int qf = 0; qf < 2; qf++)
#pragma unroll
    for (int r = 0; r < 4; r++) { mi[qf][r] = -1e30f; li[qf][r] = 0.f; }

  unsigned short* pw = Ps + wave * (16 * 136);

  for (int s = 0; s <= QT; s++) {
    const int k0 = s * 128;
    // ---- stage K[128][64] and Vt[64][128] via async global->LDS ----
#pragma unroll
    for (int it = 0; it < 4; it++) {
      int i = tid + it * 256;
      int key = i >> 3, dc = (i & 7) * 8;
      gload_lds16(qkv + bo + (size_t)(k0 + key) * 3072 + 1024 + hh * 64 + dc,
                  Ks + (size_t)i * 8);
    }
#pragma unroll
    for (int it = 0; it < 4; it++) {
      int i = tid + it * 256;
      int dr = i >> 4, kc = (i & 15) * 8;
      gload_lds16(VT + ((size_t)bh * 64 + dr) * 2048 + k0 + kc,
                  Vt + (size_t)i * 8);
    }
    __syncthreads();

#pragma unroll
    for (int qf = 0; qf < 2; qf++) {
      // ---- S = Q K^T ----
      f32x4 sc[8];
#pragma unroll
      for (int ct = 0; ct < 8; ct++) {
        const unsigned short* p = Ks + (ct * 16 + m16) * 64 + quad * 8;
        bf16x8 bk0 = *(const bf16x8*)(p);
        bf16x8 bk1 = *(const bf16x8*)(p + 32);
        f32x4 a = {0.f, 0.f, 0.f, 0.f};
        a = __builtin_amdgcn_mfma_f32_16x16x32_bf16(aQ[qf][0], bk0, a, 0, 0, 0);
        a = __builtin_amdgcn_mfma_f32_16x16x32_bf16(aQ[qf][1], bk1, a, 0, 0, 0);
        sc[ct] = a;
      }
      // ---- scale (+ mask only on diagonal stage) ----
      if (s == QT) {
#pragma unroll
        for (int ct = 0; ct < 8; ct++) {
          int key = k0 + ct * 16 + m16;
#pragma unroll
          for (int r = 0; r < 4; r++) {
            int qr = qw + qf * 16 + quad * 4 + r;
            float v = sc[ct][r] * SCL;
            sc[ct][r] = (key > qr) ? -1e30f : v;
          }
        }
      } else {
#pragma unroll
        for (int ct = 0; ct < 8; ct++)
#pragma unroll
          for (int r = 0; r < 4; r++) sc[ct][r] *= SCL;
      }
      // ---- online softmax ----
      float cand[4], rs[4];
#pragma unroll
      for (int r = 0; r < 4; r++) {
        float a0 = fmaxf(fmaxf(sc[0][r], sc[1][r]), fmaxf(sc[2][r], sc[3][r]));
        float a1 = fmaxf(fmaxf(sc[4][r], sc[5][r]), fmaxf(sc[6][r], sc[7][r]));
        cand[r] = fmaxf(a0, a1);
      }
#pragma unroll
      for (int off = 1; off < 16; off <<= 1)
#pragma unroll
        for (int r = 0; r < 4; r++)
          cand[r] = fmaxf(cand[r], __shfl_xor(cand[r], off));
      float al[4];
#pragma unroll
      for (int r = 0; r < 4; r++) {
        float mnew = fmaxf(mi[qf][r], cand[r]);
        al[r] = exp2f(mi[qf][r] - mnew);
        mi[qf][r] = mnew;
      }
#pragma unroll
      for (int ct = 0; ct < 8; ct++)
#pragma unroll
        for (int r = 0; r < 4; r++) sc[ct][r] = exp2f(sc[ct][r] - mi[qf][r]);
#pragma unroll
      for (int r = 0; r < 4; r++) {
        float a0 = sc[0][r] + sc[1][r] + sc[2][r] + sc[3][r];
        float a1 = sc[4][r] + sc[5][r] + sc[6][r] + sc[7][r];
        rs[r] = a0 + a1;
      }
#pragma unroll
      for (int off = 1; off < 16; off <<= 1)
#pragma unroll
        for (int r = 0; r < 4; r++) rs[r] += __shfl_xor(rs[r], off);
#pragma unroll
      for (int r = 0; r < 4; r++) li[qf][r] = li[qf][r] * al[r] + rs[r];
#pragma unroll
      for (int dt = 0; dt < 4; dt++)
#pragma unroll
        for (int r = 0; r < 4; r++) o[qf][dt][r] *= al[r];

      // ---- P: C-layout -> per-wave LDS -> A-layout ----
#pragma unroll
      for (int ct = 0; ct < 8; ct++)
#pragma unroll
        for (int r = 0; r < 4; r++)
          pw[(quad * 4 + r) * 136 + ct * 16 + m16] = f2bf(sc[ct][r]);
      asm volatile("s_waitcnt lgkmcnt(0)" ::: "memory");
      bf16x8 aP[4];
#pragma unroll
      for (int kp = 0; kp < 4; kp++)
        aP[kp] = *(const bf16x8*)(pw + m16 * 136 + kp * 32 + quad * 8);

      // ---- O += P V ----
#pragma unroll
      for (int dt = 0; dt < 4; dt++) {
        const unsigned short* vb = Vt + (dt * 16 + m16) * 128 + quad * 8;
#pragma unroll
        for (int kp = 0; kp < 4; kp++) {
          bf16x8 bv = *(const bf16x8*)(vb + kp * 32);
          o[qf][dt] = __builtin_amdgcn_mfma_f32_16x16x32_bf16(
              aP[kp], bv, o[qf][dt], 0, 0, 0);
        }
      }
    }
    __syncthreads();
  }

  // ---- epilogue ----
#pragma unroll
  for (int qf = 0; qf < 2; qf++)
#pragma unroll
    for (int r = 0; r < 4; r++) {
      float inv = 1.f / li[qf][r];
      int row = qw + qf * 16 + quad * 4 + r;
#pragma unroll
      for (int dt = 0; dt < 4; dt++) {
        float v = o[qf][dt][r] * inv;
        yb[((size_t)bb * 2048 + row) * 1024 + hh * 64 + dt * 16 + m16] = f2bf(v);
      }
    }
}

// ---------------- launch ----------------
extern "C" void kernel_launch(void* const* d_in, const int* in_sizes, int n_in,
                              void* d_out, int out_size, void* d_ws,
                              size_t ws_size, hipStream_t stream) {
  const float* x = (const float*)d_in[0];
  const float* wqkv = (const float*)d_in[1];
  const float* wproj = (const float*)d_in[2];
  float* out = (float*)d_out;

  unsigned short* Xb = (unsigned short*)d_ws;            // 8192*1024 (dead after gemm1)
  unsigned short* Wqkv_t = Xb + (size_t)8192 * 1024;     // 3072*1024
  unsigned short* Wp_t = Wqkv_t + (size_t)3072 * 1024;   // 1024*1024
  unsigned short* QKV = Wp_t + (size_t)1024 * 1024;      // 8192*3072
  unsigned short* Yb = QKV + (size_t)8192 * 3072;        // 8192*1024
  unsigned short* VT = Xb;                               // alias: reuse Xb

  cvt_x_kernel<<<dim3(8192), dim3(256), 0, stream>>>(x, Xb, 2097152);
  cvt_wt_kernel<<<dim3(96, 32), dim3(256), 0, stream>>>(wqkv, Wqkv_t, 1024, 3072);
  cvt_wt_kernel<<<dim3(32, 32), dim3(256), 0, stream>>>(wproj, Wp_t, 1024, 1024);

  gemm128_kernel<0><<<dim3(24, 64), dim3(256), 0, stream>>>(
      Xb, Wqkv_t, (void*)QKV, 8192, 3072, 1024);

  vtrans_kernel<<<dim3(32, 64), dim3(256), 0, stream>>>(QKV, VT);

  attn_kernel<<<dim3(16, 64), dim3(256), 0, stream>>>(QKV, VT, Yb);

  gemm128_kernel<1><<<dim3(8, 64), dim3(256), 0, stream>>>(
      Yb, Wp_t, (void*)out, 8192, 1024, 1024);
}

// Round 3
// 336.443 us; speedup vs baseline: 1.4628x; 1.4628x over previous
//
#include <hip/hip_runtime.h>
#include <hip/hip_bf16.h>
#include <cstdint>

typedef __bf16 bf16x8 __attribute__((ext_vector_type(8)));
typedef float f32x4 __attribute__((ext_vector_type(4)));
typedef unsigned short u16x8 __attribute__((ext_vector_type(8)));
typedef short s16x4 __attribute__((ext_vector_type(4)));

__device__ __forceinline__ unsigned short f2bf(float f) {
  union { float f; unsigned int u; } v; v.f = f;
  unsigned int r = v.u + 0x7fffu + ((v.u >> 16) & 1u);
  return (unsigned short)(r >> 16);
}

// async global->LDS, 16B per lane; LDS dest = wave-uniform base + lane*16.
__device__ __forceinline__ void gload_lds16(const void* g, void* l) {
  __builtin_amdgcn_global_load_lds(
      (const __attribute__((address_space(1))) unsigned int*)g,
      (__attribute__((address_space(3))) unsigned int*)l, 16, 0, 0);
}

// ---------------- convert x: fp32 -> bf16 ----------------
__global__ void cvt_x_kernel(const float* __restrict__ x,
                             unsigned short* __restrict__ xb, int n4) {
  int i = blockIdx.x * blockDim.x + threadIdx.x;
  if (i >= n4) return;
  float4 v = ((const float4*)x)[i];
  ushort4 o;
  o.x = f2bf(v.x); o.y = f2bf(v.y); o.z = f2bf(v.z); o.w = f2bf(v.w);
  ((ushort4*)xb)[i] = o;
}

// ------- transpose+convert weights: w[K][N] fp32 -> wt[N][K] bf16 -------
// rows n < n_scaled get multiplied by `scale` (folds softmax scale into Q).
__global__ void cvt_wt_kernel(const float* __restrict__ w,
                              unsigned short* __restrict__ wt, int K, int N,
                              int n_scaled, float scale) {
  __shared__ float tile[32][33];
  int nb = blockIdx.x * 32, kb = blockIdx.y * 32;
  int tx = threadIdx.x & 31, ty = threadIdx.x >> 5;
#pragma unroll
  for (int i = 0; i < 32; i += 8)
    tile[ty + i][tx] = w[(size_t)(kb + ty + i) * N + nb + tx];
  __syncthreads();
#pragma unroll
  for (int i = 0; i < 32; i += 8) {
    int n = nb + ty + i;
    float v = tile[tx][ty + i];
    if (n < n_scaled) v *= scale;
    wt[(size_t)n * K + kb + tx] = f2bf(v);
  }
}

// ---------------- 128x128 bf16 GEMM, C = A[M,K] @ Bt[N,K]^T ----------------
template <int EPI>
__global__ __launch_bounds__(256, 2)
void gemm128_kernel(const unsigned short* __restrict__ A,
                    const unsigned short* __restrict__ Bt,
                    void* __restrict__ C, int M, int N, int K) {
  __shared__ unsigned short As[128 * 72];
  __shared__ unsigned short Bs[128 * 72];
  const int tid = threadIdx.x;
  const int lane = tid & 63, wid = tid >> 6;
  const int m16 = lane & 15, quad = lane >> 4;
  const int rowBase = blockIdx.y * 128, colBase = blockIdx.x * 128;
  const int wm = (wid >> 1) * 64, wn = (wid & 1) * 64;

  f32x4 acc[4][4] = {};

  for (int k0 = 0; k0 < K; k0 += 64) {
    bf16x8 ra[4], rb[4];
#pragma unroll
    for (int it = 0; it < 4; it++) {
      int i = tid + it * 256;
      int r = i >> 3, kc = (i & 7) * 8;
      ra[it] = *(const bf16x8*)(A + (size_t)(rowBase + r) * K + k0 + kc);
      rb[it] = *(const bf16x8*)(Bt + (size_t)(colBase + r) * K + k0 + kc);
    }
#pragma unroll
    for (int it = 0; it < 4; it++) {
      int i = tid + it * 256;
      int r = i >> 3, kc = (i & 7) * 8;
      *(bf16x8*)(As + r * 72 + kc) = ra[it];
      *(bf16x8*)(Bs + r * 72 + kc) = rb[it];
    }
    __syncthreads();

    bf16x8 af[4][2], bfr[4][2];
#pragma unroll
    for (int rt = 0; rt < 4; rt++) {
      const unsigned short* p = As + (wm + rt * 16 + m16) * 72 + quad * 8;
      af[rt][0] = *(const bf16x8*)(p);
      af[rt][1] = *(const bf16x8*)(p + 32);
    }
#pragma unroll
    for (int ct = 0; ct < 4; ct++) {
      const unsigned short* p = Bs + (wn + ct * 16 + m16) * 72 + quad * 8;
      bfr[ct][0] = *(const bf16x8*)(p);
      bfr[ct][1] = *(const bf16x8*)(p + 32);
    }
#pragma unroll
    for (int rt = 0; rt < 4; rt++)
#pragma unroll
      for (int ct = 0; ct < 4; ct++) {
        acc[rt][ct] = __builtin_amdgcn_mfma_f32_16x16x32_bf16(
            af[rt][0], bfr[ct][0], acc[rt][ct], 0, 0, 0);
        acc[rt][ct] = __builtin_amdgcn_mfma_f32_16x16x32_bf16(
            af[rt][1], bfr[ct][1], acc[rt][ct], 0, 0, 0);
      }
    __syncthreads();
  }

#pragma unroll
  for (int rt = 0; rt < 4; rt++)
#pragma unroll
    for (int ct = 0; ct < 4; ct++)
#pragma unroll
      for (int r = 0; r < 4; r++) {
        int grow = rowBase + wm + rt * 16 + quad * 4 + r;
        int gcol = colBase + wn + ct * 16 + m16;
        float v = acc[rt][ct][r];
        if (EPI == 0)
          ((unsigned short*)C)[(size_t)grow * N + gcol] = f2bf(v);
        else
          ((float*)C)[(size_t)grow * N + gcol] = v;
      }
}

// ------- transpose V out of qkv: VT[(b*16+h)*64+d][t] (bf16) -------
__global__ void vtrans_kernel(const unsigned short* __restrict__ qkv,
                              unsigned short* __restrict__ VT) {
  __shared__ unsigned short tile[64 * 72];
  const int tid = threadIdx.x;
  const int bh = blockIdx.y, bb = bh >> 4, hh = bh & 15;
  const int t0 = blockIdx.x * 64;
  const size_t bo = (size_t)bb * 2048 * 3072;
#pragma unroll
  for (int it = 0; it < 2; it++) {
    int i = tid + it * 256;
    int t = i >> 3, dc = (i & 7) * 8;
    *(bf16x8*)(tile + t * 72 + dc) =
        *(const bf16x8*)(qkv + bo + (size_t)(t0 + t) * 3072 + 2048 + hh * 64 + dc);
  }
  __syncthreads();
#pragma unroll
  for (int it = 0; it < 2; it++) {
    int i = tid + it * 256;
    int d = i >> 3, tc = (i & 7) * 8;
    u16x8 v;
#pragma unroll
    for (int j = 0; j < 8; j++) v[j] = tile[(tc + j) * 72 + d];
    *(u16x8*)(VT + ((size_t)bh * 64 + d) * 2048 + t0 + tc) = v;
  }
}

// ---------------- flash attention v3 ----------------
// S^T = K·Q^T trick: S^T's C-layout (key=quad*4+r, q=m16) IS the A-operand
// layout of mfma_16x16x16 -> P never leaves registers. XOR-swizzled LDS keeps
// global_load_lds staging AND conflict-free fragment reads. Double-buffered.
// 512 threads = 8 waves x 16 q-rows; Q pre-scaled by 0.125*log2(e).
__global__ __launch_bounds__(512, 4)
void attn_kernel(const unsigned short* __restrict__ qkv,
                 const unsigned short* __restrict__ VT,
                 unsigned short* __restrict__ yb) {
  __shared__ unsigned short Ks[2][128 * 64];  // [key][d-chunk swizzled]
  __shared__ unsigned short Vt[2][64 * 128];  // [d][key-chunk swizzled]

  const int tid = threadIdx.x;
  const int lane = tid & 63, wave = tid >> 6;
  const int m16 = lane & 15, quad = lane >> 4;
  const int bh = blockIdx.y, bb = bh >> 4, hh = bh & 15;
  const int QT = (gridDim.x - 1) - blockIdx.x;  // big blocks first
  const int q0 = QT * 128;
  const size_t bo = (size_t)bb * 2048 * 3072;

  // Q B-fragment (pre-scaled in weights), resident all kernel
  const unsigned short* qb =
      qkv + bo + (size_t)(q0 + wave * 16 + m16) * 3072 + hh * 64;
  const bf16x8 aQ0 = *(const bf16x8*)(qb + quad * 8);
  const bf16x8 aQ1 = *(const bf16x8*)(qb + 32 + quad * 8);

  float mi = -1e30f, li = 0.f;
  f32x4 o[4] = {};

  // ---- swizzled staging: lane i -> LDS offset i*16B, global chunk XORed ----
  auto stage = [&](int s, int b) {
#pragma unroll
    for (int it = 0; it < 2; it++) {
      int i = tid + it * 512;
      int row = i >> 3, c = (i & 7) ^ (row & 7);
      gload_lds16(qkv + bo + (size_t)(s * 128 + row) * 3072 + 1024 + hh * 64 + c * 8,
                  &Ks[b][(size_t)i * 8]);
    }
#pragma unroll
    for (int it = 0; it < 2; it++) {
      int i = tid + it * 512;
      int row = i >> 4, c = (i & 15) ^ (row & 15);
      gload_lds16(VT + ((size_t)bh * 64 + row) * 2048 + s * 128 + c * 8,
                  &Vt[b][(size_t)i * 8]);
    }
  };

  stage(0, 0);
  const int xk = (quad ^ (m16 & 7)) * 8;  // swizzled K-chunk offset (u16)

  for (int s = 0; s <= QT; ++s) {
    __syncthreads();                       // drains loads(s), syncs compute(s-1)
    if (s < QT) stage(s + 1, (s + 1) & 1); // prefetch overlaps compute(s)
    const unsigned short* KB = Ks[s & 1];
    const unsigned short* VB = Vt[s & 1];

    // ---- S^T = K Q^T ----
    f32x4 sc[8];
#pragma unroll
    for (int ct = 0; ct < 8; ct++) {
      const unsigned short* pk = KB + (ct * 16 + m16) * 64;
      bf16x8 kf0 = *(const bf16x8*)(pk + xk);
      bf16x8 kf1 = *(const bf16x8*)(pk + (xk ^ 32));
      f32x4 a = {0.f, 0.f, 0.f, 0.f};
      a = __builtin_amdgcn_mfma_f32_16x16x32_bf16(kf0, aQ0, a, 0, 0, 0);
      a = __builtin_amdgcn_mfma_f32_16x16x32_bf16(kf1, aQ1, a, 0, 0, 0);
      sc[ct] = a;
    }

    // ---- causal mask (diagonal stage only) ----
    if (s == QT) {
      const int qloc = wave * 16 + m16;
#pragma unroll
      for (int ct = 0; ct < 8; ct++)
#pragma unroll
        for (int r = 0; r < 4; r++)
          if (ct * 16 + quad * 4 + r > qloc) sc[ct][r] = -1e30f;
    }

    // ---- online softmax (per-lane: all 32 values belong to q = m16) ----
    float h[8];
#pragma unroll
    for (int ct = 0; ct < 8; ct++)
      h[ct] = fmaxf(fmaxf(sc[ct][0], sc[ct][1]), fmaxf(sc[ct][2], sc[ct][3]));
    float cand = fmaxf(fmaxf(fmaxf(h[0], h[1]), fmaxf(h[2], h[3])),
                       fmaxf(fmaxf(h[4], h[5]), fmaxf(h[6], h[7])));
    cand = fmaxf(cand, __shfl_xor(cand, 16));
    cand = fmaxf(cand, __shfl_xor(cand, 32));
    float mnew = fmaxf(mi, cand);
    float al = exp2f(mi - mnew);
    mi = mnew;
#pragma unroll
    for (int ct = 0; ct < 8; ct++)
#pragma unroll
      for (int r = 0; r < 4; r++) sc[ct][r] = exp2f(sc[ct][r] - mi);
    float hs[8];
#pragma unroll
    for (int ct = 0; ct < 8; ct++)
      hs[ct] = (sc[ct][0] + sc[ct][1]) + (sc[ct][2] + sc[ct][3]);
    float rs = ((hs[0] + hs[1]) + (hs[2] + hs[3])) +
               ((hs[4] + hs[5]) + (hs[6] + hs[7]));
    rs += __shfl_xor(rs, 16);
    rs += __shfl_xor(rs, 32);
    li = li * al + rs;

    // ---- rescale O (O rows are q = quad*4+r: broadcast alpha) ----
    float alq[4];
#pragma unroll
    for (int r = 0; r < 4; r++) alq[r] = __shfl(al, quad * 4 + r);
#pragma unroll
    for (int dt = 0; dt < 4; dt++)
#pragma unroll
      for (int r = 0; r < 4; r++) o[dt][r] *= alq[r];

    // ---- O += P V : P^T regs are the A-operand of mfma_16x16x16 ----
#pragma unroll
    for (int ct = 0; ct < 8; ct++) {
      s16x4 aP;
#pragma unroll
      for (int r = 0; r < 4; r++) aP[r] = (short)f2bf(sc[ct][r]);
      const int csw = ((ct << 1) | (quad >> 1));
#pragma unroll
      for (int dt = 0; dt < 4; dt++) {
        int idx = (dt * 16 + m16) * 128 + ((csw ^ m16) << 3) + (quad & 1) * 4;
        s16x4 bv = *(const s16x4*)(VB + idx);
        o[dt] = __builtin_amdgcn_mfma_f32_16x16x16bf16_1k(aP, bv, o[dt], 0, 0, 0);
      }
    }
  }

  // ---- epilogue: O rows q=quad*4+r, cols d=dt*16+m16 ----
  float inv[4];
#pragma unroll
  for (int r = 0; r < 4; r++) inv[r] = 1.f / __shfl(li, quad * 4 + r);
#pragma unroll
  for (int dt = 0; dt < 4; dt++)
#pragma unroll
    for (int r = 0; r < 4; r++) {
      int row = q0 + wave * 16 + quad * 4 + r;
      yb[((size_t)bb * 2048 + row) * 1024 + hh * 64 + dt * 16 + m16] =
          f2bf(o[dt][r] * inv[r]);
    }
}

// ---------------- launch ----------------
extern "C" void kernel_launch(void* const* d_in, const int* in_sizes, int n_in,
                              void* d_out, int out_size, void* d_ws,
                              size_t ws_size, hipStream_t stream) {
  const float* x = (const float*)d_in[0];
  const float* wqkv = (const float*)d_in[1];
  const float* wproj = (const float*)d_in[2];
  float* out = (float*)d_out;

  unsigned short* Xb = (unsigned short*)d_ws;            // 8192*1024 (dead after gemm1)
  unsigned short* Wqkv_t = Xb + (size_t)8192 * 1024;     // 3072*1024
  unsigned short* Wp_t = Wqkv_t + (size_t)3072 * 1024;   // 1024*1024
  unsigned short* QKV = Wp_t + (size_t)1024 * 1024;      // 8192*3072
  unsigned short* Yb = QKV + (size_t)8192 * 3072;        // 8192*1024
  unsigned short* VT = Xb;                               // alias: reuse Xb

  const float SCL = 0.125f * 1.44269504088896f;  // d^-0.5 * log2(e)

  cvt_x_kernel<<<dim3(8192), dim3(256), 0, stream>>>(x, Xb, 2097152);
  cvt_wt_kernel<<<dim3(96, 32), dim3(256), 0, stream>>>(wqkv, Wqkv_t, 1024, 3072,
                                                        1024, SCL);
  cvt_wt_kernel<<<dim3(32, 32), dim3(256), 0, stream>>>(wproj, Wp_t, 1024, 1024,
                                                        0, 1.0f);

  gemm128_kernel<0><<<dim3(24, 64), dim3(256), 0, stream>>>(
      Xb, Wqkv_t, (void*)QKV, 8192, 3072, 1024);

  vtrans_kernel<<<dim3(32, 64), dim3(256), 0, stream>>>(QKV, VT);

  attn_kernel<<<dim3(16, 64), dim3(512), 0, stream>>>(QKV, VT, Yb);

  gemm128_kernel<1><<<dim3(8, 64), dim3(256), 0, stream>>>(
      Yb, Wp_t, (void*)out, 8192, 1024, 1024);
}